// Round 1
// baseline (594.739 us; speedup 1.0000x reference)
//
#include <hip/hip_runtime.h>
#include <type_traits>
#include <cmath>
#include <cstdint>

#define NRAYS     262144
#define HASHMAP   524288
#define DIM       256
#define NMID      6
#define MBLK      64

typedef __bf16 bf16x8  __attribute__((ext_vector_type(8)));
typedef float  floatx4 __attribute__((ext_vector_type(4)));

// ws layout in __bf16 elements:
//   [0, 16384):        W_in  fragments [nc:16][hi/lo][lane:64][j:8]  (K padded 16->32 with zeros)
//   [16384, 802816):   W_mid fragments [L:6][kc:8][nc:16][hi/lo][lane:64][j:8]
#define WIN_ELEMS   16384
#define WL_ELEMS    131072
#define WKC_ELEMS   16384
#define WNC_ELEMS   1024

// XOR-swizzled LDS index: row r (0..63), element k (0..255). 8-element (16B) groups,
// group index XORed with (r&7) -> b128 reads across 16 rows spread over all 8 chunk
// classes (2-way aliasing = free, m136), no padding needed -> exactly 64KB total LDS.
__device__ __forceinline__ int sw_idx(int r, int k) {
  return (r << 8) + ((((k >> 3) ^ (r & 7)) << 3) | (k & 7));
}

__global__ __launch_bounds__(256) void prep_weights(
    const float* __restrict__ W_in, const float* __restrict__ W_mid,
    __bf16* __restrict__ wsb)
{
  int tid = blockIdx.x * 256 + threadIdx.x;
  if (tid < 8192) {
    // W_in: (16,256) row-major [k][n]; fragment k = quad*8+j (zero for k>=16), n = nc*16 + (lane&15)
    int nc = tid >> 9;
    int pos = tid & 511;           // lane*8 + j
    int lane = pos >> 3, j = pos & 7;
    int k = ((lane >> 4) << 3) + j;          // 0..31
    int n = (nc << 4) + (lane & 15);
    float v = (k < 16) ? W_in[k * DIM + n] : 0.f;
    __bf16 hi = (__bf16)v;
    __bf16 lo = (__bf16)(v - (float)hi);
    wsb[nc * WNC_ELEMS + pos]       = hi;
    wsb[nc * WNC_ELEMS + 512 + pos] = lo;
  } else if (tid < 8192 + 393216) {
    int u = tid - 8192;
    int L    = u >> 16;
    int rem  = u & 65535;
    int kc   = rem >> 13;
    int rem2 = rem & 8191;
    int nc   = rem2 >> 9;
    int pos  = rem2 & 511;
    int lane = pos >> 3, j = pos & 7;
    int k = (kc << 5) + ((lane >> 4) << 3) + j;
    int n = (nc << 4) + (lane & 15);
    float v = W_mid[L * (DIM * DIM) + k * DIM + n];
    __bf16 hi = (__bf16)v;
    __bf16 lo = (__bf16)(v - (float)hi);
    int base = WIN_ELEMS + L * WL_ELEMS + kc * WKC_ELEMS + nc * WNC_ELEMS;
    wsb[base + pos]       = hi;
    wsb[base + 512 + pos] = lo;
  }
}

__global__ __launch_bounds__(256, 2) void mlp_fused(
    const float* __restrict__ x,
    const float* __restrict__ table1,
    const float* __restrict__ table2,
    const __bf16* __restrict__ wsb,
    const float* __restrict__ b_in,
    const float* __restrict__ b_mid,
    const float* __restrict__ W_out,
    const float* __restrict__ b_out,
    float* __restrict__ out,
    int res0, int res1, int res2, int res3)
{
  __shared__ __align__(16) __bf16 hbs[MBLK * 256];   // h split-high, swizzled [m][k]
  __shared__ __align__(16) __bf16 lbs[MBLK * 256];   // h split-low

  const int tid  = threadIdx.x;
  const int lane = tid & 63;
  const int wave = tid >> 6;
  const int col  = lane & 15;
  const int quad = lane >> 4;
  const int rbase = blockIdx.x * MBLK;

  // ---------------- hash-grid encode: 512 (ray,enc,level) tasks, 2 per thread ----------------
  #pragma unroll
  for (int i = 0; i < 2; ++i) {
    int task = tid + (i << 8);
    int r   = task & 63;
    int el  = task >> 6;           // 0..7
    int enc = el >> 2, lev = el & 3;
    const float* xp = x + (size_t)(rbase + r) * 4 + enc * 2;
    float px = xp[0], py = xp[1];
    int res = (lev == 0) ? res0 : (lev == 1) ? res1 : (lev == 2) ? res2 : res3;
    float fres = (float)res;
    float xf = px * fres, yf = py * fres;
    float xi = floorf(xf), yi = floorf(yf);
    float fx = xf - xi,  fy = yf - yi;
    uint32_t ix = (uint32_t)xi, iy = (uint32_t)yi;
    const float2* tab = (const float2*)(enc ? table2 : table1) + (size_t)lev * HASHMAP;
    float f0 = 0.f, f1 = 0.f;
    #pragma unroll
    for (int c = 0; c < 4; ++c) {                    // corners (0,0),(0,1),(1,0),(1,1)
      uint32_t c0 = (uint32_t)(c >> 1), c1 = (uint32_t)(c & 1);
      uint32_t h = ((ix + c0) ^ ((iy + c1) * 2654435761u)) & (uint32_t)(HASHMAP - 1);
      float2 v = tab[h];
      float w = (c0 ? fx : 1.f - fx) * (c1 ? fy : 1.f - fy);
      f0 += w * v.x;
      f1 += w * v.y;
    }
    int cb = enc * 8 + lev * 2;                      // emb column (concat: enc-major, level, feat)
    __bf16 h0 = (__bf16)f0;
    hbs[sw_idx(r, cb)] = h0;
    lbs[sw_idx(r, cb)] = (__bf16)(f0 - (float)h0);
    __bf16 h1 = (__bf16)f1;
    hbs[sw_idx(r, cb + 1)] = h1;
    lbs[sw_idx(r, cb + 1)] = (__bf16)(f1 - (float)h1);
  }
  // zero K-pad columns 16..31 for the first (K=32) MFMA
  for (int i = tid; i < MBLK * 16; i += 256) {
    int r = i >> 4, k = 16 + (i & 15);
    hbs[sw_idx(r, k)] = (__bf16)0.f;
    lbs[sw_idx(r, k)] = (__bf16)0.f;
  }
  __syncthreads();

  floatx4 acc[4][4];

  // One dense layer: D(64x256) = A(64xK) * B(Kx256) with split-bf16 (3 products),
  // then bias + ReLU + re-split back into LDS in A-fragment order for the next layer.
  auto run_layer = [&](auto kc_const, const __bf16* __restrict__ wbase,
                       const float* __restrict__ bias_ptr) {
    constexpr int KCOUNT = decltype(kc_const)::value;
    const floatx4 zv = {0.f, 0.f, 0.f, 0.f};
    #pragma unroll
    for (int mt = 0; mt < 4; ++mt)
      #pragma unroll
      for (int nl = 0; nl < 4; ++nl)
        acc[mt][nl] = zv;

    #pragma unroll
    for (int kc = 0; kc < KCOUNT; ++kc) {
      bf16x8 ah[4], al[4], bh[4], bl[4];
      #pragma unroll
      for (int mt = 0; mt < 4; ++mt) {
        // A-fragment: m = lane&15 (within m-tile), k = kc*32 + quad*8 + j  [verified m120]
        int idx = sw_idx(mt * 16 + col, kc * 32 + quad * 8);
        ah[mt] = *(const bf16x8*)&hbs[idx];
        al[mt] = *(const bf16x8*)&lbs[idx];
      }
      #pragma unroll
      for (int nl = 0; nl < 4; ++nl) {
        // B-fragment pre-permuted in ws: one dwordx4 per lane
        const __bf16* p = wbase + kc * WKC_ELEMS + (wave * 4 + nl) * WNC_ELEMS + lane * 8;
        bh[nl] = *(const bf16x8*)p;
        bl[nl] = *(const bf16x8*)(p + 512);
      }
      #pragma unroll
      for (int nl = 0; nl < 4; ++nl)
        #pragma unroll
        for (int mt = 0; mt < 4; ++mt) {
          acc[mt][nl] = __builtin_amdgcn_mfma_f32_16x16x32_bf16(ah[mt], bh[nl], acc[mt][nl], 0, 0, 0);
          acc[mt][nl] = __builtin_amdgcn_mfma_f32_16x16x32_bf16(ah[mt], bl[nl], acc[mt][nl], 0, 0, 0);
          acc[mt][nl] = __builtin_amdgcn_mfma_f32_16x16x32_bf16(al[mt], bh[nl], acc[mt][nl], 0, 0, 0);
        }
    }
    __syncthreads();   // all waves done reading hbs/lbs before overwrite
    #pragma unroll
    for (int nl = 0; nl < 4; ++nl) {
      int n = wave * 64 + nl * 16 + col;
      float bias = bias_ptr[n];
      #pragma unroll
      for (int mt = 0; mt < 4; ++mt) {
        #pragma unroll
        for (int r = 0; r < 4; ++r) {
          // D layout: col = lane&15, row = quad*4 + r  [verified m89]
          int m = mt * 16 + quad * 4 + r;
          float hv = acc[mt][nl][r] + bias;
          hv = fmaxf(hv, 0.f);                 // ReLU is applied pre-matmul next layer
          __bf16 hi = (__bf16)hv;
          int idx = sw_idx(m, n);
          hbs[idx] = hi;
          lbs[idx] = (__bf16)(hv - (float)hi);
        }
      }
    }
    __syncthreads();
  };

  run_layer(std::integral_constant<int, 1>{}, wsb, b_in);
  #pragma clang loop unroll(disable)
  for (int L = 0; L < NMID; ++L)
    run_layer(std::integral_constant<int, 8>{}, wsb + WIN_ELEMS + L * WL_ELEMS, b_mid + L * DIM);

  // ---------------- output layer: out = relu(h) . W_out + b_out (h already relu'd in LDS) ----
  {
    int m = tid >> 2, seg = tid & 3;          // same-m threads adjacent -> shuffle reduce
    float sum = 0.f;
    #pragma unroll 4
    for (int i = 0; i < 64; ++i) {
      int k = (seg << 6) + ((i + m) & 63);    // rotate k by m to spread LDS banks
      int idx = sw_idx(m, k);
      float hv = (float)hbs[idx] + (float)lbs[idx];
      sum += hv * W_out[k];
    }
    sum += __shfl_xor(sum, 1);
    sum += __shfl_xor(sum, 2);
    if (seg == 0) out[rbase + m] = sum + b_out[0];
  }
}

extern "C" void kernel_launch(void* const* d_in, const int* in_sizes, int n_in,
                              void* d_out, int out_size, void* d_ws, size_t ws_size,
                              hipStream_t stream)
{
  const float* x      = (const float*)d_in[0];
  const float* table1 = (const float*)d_in[1];
  const float* table2 = (const float*)d_in[2];
  const float* W_in   = (const float*)d_in[3];
  const float* b_in   = (const float*)d_in[4];
  const float* W_mid  = (const float*)d_in[5];
  const float* b_mid  = (const float*)d_in[6];
  const float* W_out  = (const float*)d_in[7];
  const float* b_out  = (const float*)d_in[8];
  float* out  = (float*)d_out;
  __bf16* wsb = (__bf16*)d_ws;

  // Resolutions: identical double-precision op sequence as the Python module (same libm),
  // so any floor() boundary case resolves the same way.
  double b = exp((log(512.0) - log(16.0)) / 3.0);
  int res[4];
  for (int l = 0; l < 4; ++l) res[l] = (int)floor(16.0 * pow(b, (double)l));

  int prep_total = 8192 + 393216;
  prep_weights<<<(prep_total + 255) / 256, 256, 0, stream>>>(W_in, W_mid, wsb);
  mlp_fused<<<NRAYS / MBLK, 256, 0, stream>>>(x, table1, table2, wsb, b_in, b_mid,
                                              W_out, b_out, out,
                                              res[0], res[1], res[2], res[3]);
}

// Round 4
// 585.179 us; speedup vs baseline: 1.0163x; 1.0163x over previous
//
#include <hip/hip_runtime.h>
#include <type_traits>
#include <cmath>
#include <cstdint>

#define NRAYS     262144
#define HASHMAP   524288
#define DIM       256
#define NMID      6
#define MBLK      64

typedef __bf16 bf16x8  __attribute__((ext_vector_type(8)));
typedef float  floatx4 __attribute__((ext_vector_type(4)));

// ws layout in __bf16 elements:
//   [0, 16384):        W_in  fragments [nc:16][hi/lo][lane:64][j:8]  (K padded 16->32 with zeros)
//   [16384, 802816):   W_mid fragments [L:6][kc:8][nc:16][hi/lo][lane:64][j:8]
#define WIN_ELEMS   16384
#define WL_ELEMS    131072
#define WKC_ELEMS   16384
#define WNC_ELEMS   1024

// XOR-swizzled LDS index: row r (0..63), element k (0..255), 8-elem (16B) groups.
// R4 change (the ONLY diff vs the passing R1 kernel): XOR key is the Gray code
// (r ^ (r>>1)) & 7 instead of r & 7. Epilogue stores hit rows {mt*16+quad*4+e};
// with r&7 the quad pairs (0,2),(1,3) share keys -> 4 lanes/bank (4-way, 1.58x,
// measured 4.1e7 conflicts). Gray keys per quad differ pairwise in bits 1-2
// ({g, g^6, g^4, g^2}) -> 8 distinct groups -> 2 lanes/bank = free (m136).
// A-reads: gray over 16 rows still covers each key exactly twice -> <=2-way, free.
__device__ __forceinline__ int sw_idx(int r, int k) {
  int s = (r ^ (r >> 1)) & 7;
  return (r << 8) + ((((k >> 3) ^ s) << 3) | (k & 7));
}

__global__ __launch_bounds__(256) void prep_weights(
    const float* __restrict__ W_in, const float* __restrict__ W_mid,
    __bf16* __restrict__ wsb)
{
  int tid = blockIdx.x * 256 + threadIdx.x;
  if (tid < 8192) {
    // W_in: (16,256) row-major [k][n]; fragment k = quad*8+j (zero for k>=16), n = nc*16 + (lane&15)
    int nc = tid >> 9;
    int pos = tid & 511;           // lane*8 + j
    int lane = pos >> 3, j = pos & 7;
    int k = ((lane >> 4) << 3) + j;          // 0..31
    int n = (nc << 4) + (lane & 15);
    float v = (k < 16) ? W_in[k * DIM + n] : 0.f;
    __bf16 hi = (__bf16)v;
    __bf16 lo = (__bf16)(v - (float)hi);
    wsb[nc * WNC_ELEMS + pos]       = hi;
    wsb[nc * WNC_ELEMS + 512 + pos] = lo;
  } else if (tid < 8192 + 393216) {
    int u = tid - 8192;
    int L    = u >> 16;
    int rem  = u & 65535;
    int kc   = rem >> 13;
    int rem2 = rem & 8191;
    int nc   = rem2 >> 9;
    int pos  = rem2 & 511;
    int lane = pos >> 3, j = pos & 7;
    int k = (kc << 5) + ((lane >> 4) << 3) + j;
    int n = (nc << 4) + (lane & 15);
    float v = W_mid[L * (DIM * DIM) + k * DIM + n];
    __bf16 hi = (__bf16)v;
    __bf16 lo = (__bf16)(v - (float)hi);
    int base = WIN_ELEMS + L * WL_ELEMS + kc * WKC_ELEMS + nc * WNC_ELEMS;
    wsb[base + pos]       = hi;
    wsb[base + 512 + pos] = lo;
  }
}

__global__ __launch_bounds__(256, 2) void mlp_fused(
    const float* __restrict__ x,
    const float* __restrict__ table1,
    const float* __restrict__ table2,
    const __bf16* __restrict__ wsb,
    const float* __restrict__ b_in,
    const float* __restrict__ b_mid,
    const float* __restrict__ W_out,
    const float* __restrict__ b_out,
    float* __restrict__ out,
    int res0, int res1, int res2, int res3)
{
  __shared__ __align__(16) __bf16 hbs[MBLK * 256];   // h split-high, swizzled [m][k]
  __shared__ __align__(16) __bf16 lbs[MBLK * 256];   // h split-low

  const int tid  = threadIdx.x;
  const int lane = tid & 63;
  const int wave = tid >> 6;
  const int col  = lane & 15;
  const int quad = lane >> 4;
  const int rbase = blockIdx.x * MBLK;

  // ---------------- hash-grid encode: 512 (ray,enc,level) tasks, 2 per thread ----------------
  #pragma unroll
  for (int i = 0; i < 2; ++i) {
    int task = tid + (i << 8);
    int r   = task & 63;
    int el  = task >> 6;           // 0..7
    int enc = el >> 2, lev = el & 3;
    const float* xp = x + (size_t)(rbase + r) * 4 + enc * 2;
    float px = xp[0], py = xp[1];
    int res = (lev == 0) ? res0 : (lev == 1) ? res1 : (lev == 2) ? res2 : res3;
    float fres = (float)res;
    float xf = px * fres, yf = py * fres;
    float xi = floorf(xf), yi = floorf(yf);
    float fx = xf - xi,  fy = yf - yi;
    uint32_t ix = (uint32_t)xi, iy = (uint32_t)yi;
    const float2* tab = (const float2*)(enc ? table2 : table1) + (size_t)lev * HASHMAP;
    float f0 = 0.f, f1 = 0.f;
    #pragma unroll
    for (int c = 0; c < 4; ++c) {                    // corners (0,0),(0,1),(1,0),(1,1)
      uint32_t c0 = (uint32_t)(c >> 1), c1 = (uint32_t)(c & 1);
      uint32_t h = ((ix + c0) ^ ((iy + c1) * 2654435761u)) & (uint32_t)(HASHMAP - 1);
      float2 v = tab[h];
      float w = (c0 ? fx : 1.f - fx) * (c1 ? fy : 1.f - fy);
      f0 += w * v.x;
      f1 += w * v.y;
    }
    int cb = enc * 8 + lev * 2;                      // emb column (concat: enc-major, level, feat)
    __bf16 h0 = (__bf16)f0;
    hbs[sw_idx(r, cb)] = h0;
    lbs[sw_idx(r, cb)] = (__bf16)(f0 - (float)h0);
    __bf16 h1 = (__bf16)f1;
    hbs[sw_idx(r, cb + 1)] = h1;
    lbs[sw_idx(r, cb + 1)] = (__bf16)(f1 - (float)h1);
  }
  // zero K-pad columns 16..31 for the first (K=32) MFMA
  for (int i = tid; i < MBLK * 16; i += 256) {
    int r = i >> 4, k = 16 + (i & 15);
    hbs[sw_idx(r, k)] = (__bf16)0.f;
    lbs[sw_idx(r, k)] = (__bf16)0.f;
  }
  __syncthreads();

  floatx4 acc[4][4];

  // One dense layer: D(64x256) = A(64xK) * B(Kx256) with split-bf16 (3 products),
  // then bias + ReLU + re-split back into LDS in A-fragment order for the next layer.
  auto run_layer = [&](auto kc_const, const __bf16* __restrict__ wbase,
                       const float* __restrict__ bias_ptr) {
    constexpr int KCOUNT = decltype(kc_const)::value;
    const floatx4 zv = {0.f, 0.f, 0.f, 0.f};
    #pragma unroll
    for (int mt = 0; mt < 4; ++mt)
      #pragma unroll
      for (int nl = 0; nl < 4; ++nl)
        acc[mt][nl] = zv;

    #pragma unroll
    for (int kc = 0; kc < KCOUNT; ++kc) {
      bf16x8 ah[4], al[4], bh[4], bl[4];
      #pragma unroll
      for (int mt = 0; mt < 4; ++mt) {
        // A-fragment: m = lane&15 (within m-tile), k = kc*32 + quad*8 + j  [verified m120]
        int idx = sw_idx(mt * 16 + col, kc * 32 + quad * 8);
        ah[mt] = *(const bf16x8*)&hbs[idx];
        al[mt] = *(const bf16x8*)&lbs[idx];
      }
      #pragma unroll
      for (int nl = 0; nl < 4; ++nl) {
        // B-fragment pre-permuted in ws: one dwordx4 per lane
        const __bf16* p = wbase + kc * WKC_ELEMS + (wave * 4 + nl) * WNC_ELEMS + lane * 8;
        bh[nl] = *(const bf16x8*)p;
        bl[nl] = *(const bf16x8*)(p + 512);
      }
      #pragma unroll
      for (int nl = 0; nl < 4; ++nl)
        #pragma unroll
        for (int mt = 0; mt < 4; ++mt) {
          acc[mt][nl] = __builtin_amdgcn_mfma_f32_16x16x32_bf16(ah[mt], bh[nl], acc[mt][nl], 0, 0, 0);
          acc[mt][nl] = __builtin_amdgcn_mfma_f32_16x16x32_bf16(ah[mt], bl[nl], acc[mt][nl], 0, 0, 0);
          acc[mt][nl] = __builtin_amdgcn_mfma_f32_16x16x32_bf16(al[mt], bh[nl], acc[mt][nl], 0, 0, 0);
        }
    }
    __syncthreads();   // all waves done reading hbs/lbs before overwrite
    #pragma unroll
    for (int nl = 0; nl < 4; ++nl) {
      int n = wave * 64 + nl * 16 + col;
      float bias = bias_ptr[n];
      #pragma unroll
      for (int mt = 0; mt < 4; ++mt) {
        #pragma unroll
        for (int r = 0; r < 4; ++r) {
          // D layout: col = lane&15, row = quad*4 + r  [verified m89]
          int m = mt * 16 + quad * 4 + r;
          float hv = acc[mt][nl][r] + bias;
          hv = fmaxf(hv, 0.f);                 // ReLU is applied pre-matmul next layer
          __bf16 hi = (__bf16)hv;
          int idx = sw_idx(m, n);
          hbs[idx] = hi;
          lbs[idx] = (__bf16)(hv - (float)hi);
        }
      }
    }
    __syncthreads();
  };

  run_layer(std::integral_constant<int, 1>{}, wsb, b_in);
  #pragma clang loop unroll(disable)
  for (int L = 0; L < NMID; ++L)
    run_layer(std::integral_constant<int, 8>{}, wsb + WIN_ELEMS + L * WL_ELEMS, b_mid + L * DIM);

  // ---------------- output layer: out = relu(h) . W_out + b_out (h already relu'd in LDS) ----
  {
    int m = tid >> 2, seg = tid & 3;          // same-m threads adjacent -> shuffle reduce
    float sum = 0.f;
    #pragma unroll 4
    for (int i = 0; i < 64; ++i) {
      int k = (seg << 6) + ((i + m) & 63);    // rotate k by m to spread LDS banks
      int idx = sw_idx(m, k);
      float hv = (float)hbs[idx] + (float)lbs[idx];
      sum += hv * W_out[k];
    }
    sum += __shfl_xor(sum, 1);
    sum += __shfl_xor(sum, 2);
    if (seg == 0) out[rbase + m] = sum + b_out[0];
  }
}

extern "C" void kernel_launch(void* const* d_in, const int* in_sizes, int n_in,
                              void* d_out, int out_size, void* d_ws, size_t ws_size,
                              hipStream_t stream)
{
  const float* x      = (const float*)d_in[0];
  const float* table1 = (const float*)d_in[1];
  const float* table2 = (const float*)d_in[2];
  const float* W_in   = (const float*)d_in[3];
  const float* b_in   = (const float*)d_in[4];
  const float* W_mid  = (const float*)d_in[5];
  const float* b_mid  = (const float*)d_in[6];
  const float* W_out  = (const float*)d_in[7];
  const float* b_out  = (const float*)d_in[8];
  float* out  = (float*)d_out;
  __bf16* wsb = (__bf16*)d_ws;

  // Resolutions: identical double-precision op sequence as the Python module (same libm),
  // so any floor() boundary case resolves the same way.
  double b = exp((log(512.0) - log(16.0)) / 3.0);
  int res[4];
  for (int l = 0; l < 4; ++l) res[l] = (int)floor(16.0 * pow(b, (double)l));

  int prep_total = 8192 + 393216;
  prep_weights<<<(prep_total + 255) / 256, 256, 0, stream>>>(W_in, W_mid, wsb);
  mlp_fused<<<NRAYS / MBLK, 256, 0, stream>>>(x, table1, table2, wsb, b_in, b_mid,
                                              W_out, b_out, out,
                                              res[0], res[1], res[2], res[3]);
}